// Round 6
// baseline (273.110 us; speedup 1.0000x reference)
//
#include <hip/hip_runtime.h>

// MultiHeadAttention: B=2, S=2048, H=16, d=64, D=1024. I/O fp32; compute bf16 MFMA.
// [cvt] fp32->bf16 -> [qkv] X@W^T+b (Q pre-scaled by 0.125*log2e; K row-major;
// V as [B,H,64,2048]) -> [attn] wave-private flash attention, fixed-max softmax
// -> [proj] O@Wo^T+bo -> fp32 d_out.

typedef unsigned short u16;
typedef __attribute__((ext_vector_type(8))) short short8;   // 8 bf16 (MFMA A/B frag)
typedef __attribute__((ext_vector_type(4))) float floatx4;  // MFMA C/D frag

__device__ __forceinline__ float bf2f(u16 x) {
  return __uint_as_float(((unsigned)x) << 16);
}
__device__ __forceinline__ u16 f2bf(float f) {
  unsigned x = __float_as_uint(f);
  return (u16)((x + 0x7fffu + ((x >> 16) & 1u)) >> 16);  // RNE
}
__device__ __forceinline__ void gll16(const u16* g, u16* lds) {
  __builtin_amdgcn_global_load_lds((const __attribute__((address_space(1))) void*)g,
                                   (__attribute__((address_space(3))) void*)lds,
                                   16, 0, 0);
}
// LDS-only fence: compiler reorder barrier + wait DS ops; does NOT drain vmcnt,
// so global prefetch loads stay in flight (unlike __threadfence_block).
#define DSFENCE() __asm__ volatile("s_waitcnt lgkmcnt(0)" ::: "memory")

// ---------------------------------------------------------------------------
// fp32 -> bf16 of all 11 inputs. 16388 blocks x 256 thr x 4 elem, exact cover.
// ---------------------------------------------------------------------------
__global__ __launch_bounds__(256) void cvt_kernel(
    const float* __restrict__ q, const float* __restrict__ k, const float* __restrict__ v,
    const float* __restrict__ wq, const float* __restrict__ wk,
    const float* __restrict__ wv, const float* __restrict__ wo,
    const float* __restrict__ bq, const float* __restrict__ bk,
    const float* __restrict__ bv, const float* __restrict__ bo,
    u16* __restrict__ ws) {
  const int i4 = (blockIdx.x * 256 + threadIdx.x) * 4;
  const float* src;
  u16* dst;
  int local;
  if (i4 < 4194304)        { src = q;  dst = ws;            local = i4; }
  else if (i4 < 8388608)   { src = k;  dst = ws + 4194304;  local = i4 - 4194304; }
  else if (i4 < 12582912)  { src = v;  dst = ws + 8388608;  local = i4 - 8388608; }
  else if (i4 < 13631488)  { src = wq; dst = ws + 12582912; local = i4 - 12582912; }
  else if (i4 < 14680064)  { src = wk; dst = ws + 13631488; local = i4 - 13631488; }
  else if (i4 < 15728640)  { src = wv; dst = ws + 14680064; local = i4 - 14680064; }
  else if (i4 < 16777216)  { src = wo; dst = ws + 15728640; local = i4 - 15728640; }
  else if (i4 < 16778240)  { src = bq; dst = ws + 16777216; local = i4 - 16777216; }
  else if (i4 < 16779264)  { src = bk; dst = ws + 16779264; local = i4 - 16778240; }
  else if (i4 < 16780288)  { src = bv; dst = ws + 16781312; local = i4 - 16779264; }
  else                     { src = bo; dst = ws + 16783360; local = i4 - 16780288; }
  const float4 f = *(const float4*)(src + local);
  ushort4 o;
  o.x = f2bf(f.x); o.y = f2bf(f.y); o.z = f2bf(f.z); o.w = f2bf(f.w);
  *(ushort4*)(dst + local) = o;
}

// ---------------------------------------------------------------------------
// GEMM tile (m97 structure): out[m][n] = (X[m][:].W[n][:] + bias[n]) * oscale
// 256 thr (2x2 waves of 64x64), tile 128x128, BK=32, gll16 width-16 staging.
// mode 0: bf16 row-major. mode 1: bf16 [b][h][dd][s]. mode 2: fp32 row-major.
// ---------------------------------------------------------------------------
__device__ __forceinline__ void gemm_tile(
    const u16* __restrict__ X, const u16* __restrict__ W,
    const u16* __restrict__ bias, u16* __restrict__ out16, float* __restrict__ out32,
    int row0, int col0, int mode, float oscale, u16* As, u16* Bs) {
  const int tid = threadIdx.x;
  const int w = tid >> 6, l = tid & 63;
  const int lan = l & 15, quad = l >> 4;
  const int wm = w & 1, wn = w >> 1;

  floatx4 acc[4][4];
#pragma unroll
  for (int i = 0; i < 4; ++i)
#pragma unroll
    for (int j = 0; j < 4; ++j) acc[i][j] = (floatx4)0.0f;

  const int r0 = tid >> 2, kq0 = tid & 3;
  const int r1 = (tid + 256) >> 2;
  u16* aB0 = As + w * 512;
  u16* aB1 = As + 2048 + w * 512;
  u16* bB0 = Bs + w * 512;
  u16* bB1 = Bs + 2048 + w * 512;
  const u16* Xa0 = X + (size_t)(row0 + r0) * 1024 + kq0 * 8;
  const u16* Xa1 = X + (size_t)(row0 + r1) * 1024 + kq0 * 8;
  const u16* Wb0 = W + (size_t)(col0 + r0) * 1024 + kq0 * 8;
  const u16* Wb1 = W + (size_t)(col0 + r1) * 1024 + kq0 * 8;

  for (int kt = 0; kt < 32; ++kt) {
    gll16(Xa0 + kt * 32, aB0);
    gll16(Xa1 + kt * 32, aB1);
    gll16(Wb0 + kt * 32, bB0);
    gll16(Wb1 + kt * 32, bB1);
    __syncthreads();

    short8 af[4], bfr[4];
#pragma unroll
    for (int i = 0; i < 4; ++i)
      af[i] = *(const short8*)(As + (wm * 64 + i * 16 + lan) * 32 + quad * 8);
#pragma unroll
    for (int j = 0; j < 4; ++j)
      bfr[j] = *(const short8*)(Bs + (wn * 64 + j * 16 + lan) * 32 + quad * 8);
#pragma unroll
    for (int i = 0; i < 4; ++i)
#pragma unroll
      for (int j = 0; j < 4; ++j)
        acc[i][j] = __builtin_amdgcn_mfma_f32_16x16x32_bf16(af[i], bfr[j], acc[i][j], 0, 0, 0);
    __syncthreads();
  }

#pragma unroll
  for (int i = 0; i < 4; ++i) {
    const int mb = row0 + wm * 64 + i * 16 + quad * 4;
#pragma unroll
    for (int j = 0; j < 4; ++j) {
      const int n = col0 + wn * 64 + j * 16 + lan;
      const float bv = bf2f(bias[n]);
      if (mode == 0) {
#pragma unroll
        for (int r = 0; r < 4; ++r)
          out16[(size_t)(mb + r) * 1024 + n] = f2bf((acc[i][j][r] + bv) * oscale);
      } else if (mode == 1) {
        const int b = mb >> 11, s = mb & 2047;
        const int h = n >> 6, dd = n & 63;
        ushort4 v;
        v.x = f2bf(acc[i][j][0] + bv);
        v.y = f2bf(acc[i][j][1] + bv);
        v.z = f2bf(acc[i][j][2] + bv);
        v.w = f2bf(acc[i][j][3] + bv);
        *(ushort4*)(out16 + (size_t)((b * 16 + h) * 64 + dd) * 2048 + s) = v;
      } else {
#pragma unroll
        for (int r = 0; r < 4; ++r)
          out32[(size_t)(mb + r) * 1024 + n] = acc[i][j][r] + bv;
      }
    }
  }
}

__global__ __launch_bounds__(256) void qkv_kernel(
    const u16* __restrict__ xq, const u16* __restrict__ xk, const u16* __restrict__ xv,
    const u16* __restrict__ Wq, const u16* __restrict__ Wk, const u16* __restrict__ Wv,
    const u16* __restrict__ bq, const u16* __restrict__ bk, const u16* __restrict__ bv,
    u16* __restrict__ Qo, u16* __restrict__ Ko, u16* __restrict__ Vto) {
  __shared__ __align__(16) u16 As[128 * 32];
  __shared__ __align__(16) u16 Bs[128 * 32];
  const int bx = blockIdx.x;           // 0..767
  const int tile_m = bx / 24;
  const int rem = bx - tile_m * 24;
  const int which = rem >> 3;          // 0=Q 1=K 2=V
  const int col0 = (rem & 7) * 128;
  const u16* X = which == 0 ? xq : (which == 1 ? xk : xv);
  const u16* W = which == 0 ? Wq : (which == 1 ? Wk : Wv);
  const u16* bias = which == 0 ? bq : (which == 1 ? bk : bv);
  u16* out = which == 0 ? Qo : (which == 1 ? Ko : Vto);
  const float C = 0.125f * 1.4426950408889634f;  // fold scale*log2e into Q
  gemm_tile(X, W, bias, out, nullptr, tile_m * 128, col0, which == 2 ? 1 : 0,
            which == 0 ? C : 1.0f, As, Bs);
}

__global__ __launch_bounds__(256) void proj_kernel(
    const u16* __restrict__ X, const u16* __restrict__ W,
    const u16* __restrict__ bias, float* __restrict__ out) {
  __shared__ __align__(16) u16 As[128 * 32];
  __shared__ __align__(16) u16 Bs[128 * 32];
  const int bx = blockIdx.x;  // 0..255
  gemm_tile(X, W, bias, nullptr, out, (bx >> 3) * 128, (bx & 7) * 128, 2, 1.0f, As, Bs);
}

// ---------------------------------------------------------------------------
// Flash attention v4: wave-private key-split. Block = 64 q-rows; wave w owns keys
// [w*512,(w+1)*512) in 16 tiles of 32. Fixed-max softmax (p=exp2(C*qk-16); C in Q,
// -16 in sacc init) makes partial O/l additive across waves -> single end merge.
// Q in registers; per-wave LDS regions; NO barriers in the K-loop.
//  Ks[w]: 32key x 72  (144B rows, frag reads 2-way)   4608 B/wave
//  Vs[w]: 64dd  x 40  ( 80B rows, 16B-aligned, 2-way) 5120 B/wave
//  Ps[w]: 64q   x 40  (P writes ~4-way b16, reads 2-way) 5120 B/wave
//  total 4*(14848) + Lbuf 1KB = 60416 B -> 2 blocks/CU, 8 waves/CU.
// ---------------------------------------------------------------------------
#define FIXMAX 16.0f
__global__ __launch_bounds__(256, 2) void attn_kernel(
    const u16* __restrict__ Q, const u16* __restrict__ K,
    const u16* __restrict__ Vt, u16* __restrict__ O) {
  __shared__ __align__(16) u16 lds[30208];  // Ks 0..9215 | Vs 9216..19455 | Ps 19456..30207
  __shared__ float Lbuf[256];               // per-wave l partials [w][64]
  const int tid = threadIdx.x;
  const int w = tid >> 6, l = tid & 63;
  const int lan = l & 15, quad = l >> 4;
  const int q0 = blockIdx.x * 64;
  const int bh = blockIdx.y;
  const int b = bh >> 4, h = bh & 15;
  const u16* Qg = Q + (size_t)(b * 2048 + q0) * 1024 + h * 64;
  const u16* Kg = K + (size_t)(b * 2048 + w * 512) * 1024 + h * 64;  // wave's key range
  const u16* Vg = Vt + (size_t)((b * 16 + h) * 64) * 2048 + w * 512;
  u16* Ksw = lds + w * 2304;
  u16* Vsw = lds + 9216 + w * 2560;
  u16* Psw = lds + 19456 + w * 2560;

  // Q -> registers: A-frag aq[mi][kk] = Q[q=mi*16+lan][dd=kk*32+quad*8 ..+8]
  short8 aq[4][2];
#pragma unroll
  for (int mi = 0; mi < 4; ++mi)
#pragma unroll
    for (int kk = 0; kk < 2; ++kk)
      aq[mi][kk] = *(const short8*)(Qg + (size_t)(mi * 16 + lan) * 1024 + kk * 32 + quad * 8);

  float lrun[4][4];
  floatx4 oacc[4][4];
#pragma unroll
  for (int mi = 0; mi < 4; ++mi) {
#pragma unroll
    for (int r = 0; r < 4; ++r) lrun[mi][r] = 0.f;
#pragma unroll
    for (int nd = 0; nd < 4; ++nd) oacc[mi][nd] = (floatx4)0.0f;
  }

  // staging chunk maps (per lane, 4 chunks each of 16B)
  const int krow = l >> 3, kcol = (l & 7) * 8;  // K: +p*8 rows
  const int vdd = l >> 2, vcol = (l & 3) * 8;   // V: +p*16 rows

  // prefetch tile 0
  short8 kp[4], vp[4];
#pragma unroll
  for (int p = 0; p < 4; ++p) {
    kp[p] = *(const short8*)(Kg + (size_t)(p * 8 + krow) * 1024 + kcol);
    vp[p] = *(const short8*)(Vg + (size_t)(p * 16 + vdd) * 2048 + vcol);
  }

  for (int kt = 0; kt < 16; ++kt) {
    DSFENCE();  // prior iter's pa/vb reads drained before overwrite (compiler+HW order)
#pragma unroll
    for (int p = 0; p < 4; ++p) {
      *(short8*)(Ksw + (p * 8 + krow) * 72 + kcol) = kp[p];
      *(short8*)(Vsw + (p * 16 + vdd) * 40 + vcol) = vp[p];
    }
    DSFENCE();  // staging visible before fragment reads

    // prefetch next tile (global loads overlap compute; vmcnt untouched by fences)
    const int kn = kt < 15 ? kt + 1 : 15;
#pragma unroll
    for (int p = 0; p < 4; ++p) {
      kp[p] = *(const short8*)(Kg + (size_t)(kn * 32 + p * 8 + krow) * 1024 + kcol);
      vp[p] = *(const short8*)(Vg + (size_t)(p * 16 + vdd) * 2048 + kn * 32 + vcol);
    }

    // S = Q K^T : 64q x 32keys. B-frag: K[n=key][k=dd]
    short8 bkf[2][2];
#pragma unroll
    for (int nj = 0; nj < 2; ++nj)
#pragma unroll
      for (int kk = 0; kk < 2; ++kk)
        bkf[nj][kk] = *(const short8*)(Ksw + (nj * 16 + lan) * 72 + kk * 32 + quad * 8);
    floatx4 sacc[4][2];
#pragma unroll
    for (int mi = 0; mi < 4; ++mi)
#pragma unroll
      for (int nj = 0; nj < 2; ++nj) sacc[mi][nj] = (floatx4)(-FIXMAX);
#pragma unroll
    for (int kk = 0; kk < 2; ++kk)
#pragma unroll
      for (int mi = 0; mi < 4; ++mi)
#pragma unroll
        for (int nj = 0; nj < 2; ++nj)
          sacc[mi][nj] =
              __builtin_amdgcn_mfma_f32_16x16x32_bf16(aq[mi][kk], bkf[nj][kk], sacc[mi][nj], 0, 0, 0);

    // fixed-max softmax; C/D: row=quad*4+r, col=lan
#pragma unroll
    for (int mi = 0; mi < 4; ++mi)
#pragma unroll
      for (int r = 0; r < 4; ++r) {
        const float p0 = exp2f(sacc[mi][0][r]);
        const float p1 = exp2f(sacc[mi][1][r]);
        lrun[mi][r] += p0 + p1;
        const int qrow = mi * 16 + quad * 4 + r;
        Psw[qrow * 40 + lan] = f2bf(p0);
        Psw[qrow * 40 + 16 + lan] = f2bf(p1);
      }
    DSFENCE();  // P visible before A-frag reads

    // O += P V : A-frag P[m=q][k=key(32)], B-frag V[n=dd][k=key]
    short8 pa[4], vb[4];
#pragma unroll
    for (int mi = 0; mi < 4; ++mi)
      pa[mi] = *(const short8*)(Psw + (mi * 16 + lan) * 40 + quad * 8);
#pragma unroll
    for (int nd = 0; nd < 4; ++nd)
      vb[nd] = *(const short8*)(Vsw + (nd * 16 + lan) * 40 + quad * 8);
#pragma unroll
    for (int mi = 0; mi < 4; ++mi)
#pragma unroll
      for (int nd = 0; nd < 4; ++nd)
        oacc[mi][nd] = __builtin_amdgcn_mfma_f32_16x16x32_bf16(pa[mi], vb[nd], oacc[mi][nd], 0, 0, 0);
  }

  // ---- merge across waves (fixed-max => plain sums) ----
#pragma unroll
  for (int mi = 0; mi < 4; ++mi)
#pragma unroll
    for (int r = 0; r < 4; ++r) {
      float ls = lrun[mi][r];
#pragma unroll
      for (int d = 1; d < 16; d <<= 1) ls += __shfl_xor(ls, d);
      if (lan == 0) Lbuf[w * 64 + mi * 16 + quad * 4 + r] = ls;
    }
  __syncthreads();
  const int qm = tid >> 2, d0 = (tid & 3) * 4;
  const float linv =
      1.0f / (Lbuf[qm] + Lbuf[64 + qm] + Lbuf[128 + qm] + Lbuf[192 + qm]);
  float* Obuf = (float*)(lds + 19456);  // reuse Ps region: [w][64 rows][17 f32]

#pragma unroll
  for (int nd = 0; nd < 4; ++nd) {
    __syncthreads();  // previous read phase done before overwrite
#pragma unroll
    for (int mi = 0; mi < 4; ++mi)
#pragma unroll
      for (int r = 0; r < 4; ++r)
        Obuf[w * 1088 + (mi * 16 + quad * 4 + r) * 17 + lan] = oacc[mi][nd][r];
    __syncthreads();
    ushort4 ov;
#pragma unroll
    for (int e = 0; e < 4; ++e) {
      const float s = Obuf[qm * 17 + d0 + e] + Obuf[1088 + qm * 17 + d0 + e] +
                      Obuf[2176 + qm * 17 + d0 + e] + Obuf[3264 + qm * 17 + d0 + e];
      ((u16*)&ov)[e] = f2bf(s * linv);
    }
    *(ushort4*)(O + (size_t)(b * 2048 + q0 + qm) * 1024 + h * 64 + nd * 16 + d0) = ov;
  }
}

extern "C" void kernel_launch(void* const* d_in, const int* in_sizes, int n_in,
                              void* d_out, int out_size, void* d_ws, size_t ws_size,
                              hipStream_t stream) {
  const float* query = (const float*)d_in[0];
  const float* key_ = (const float*)d_in[1];
  const float* value = (const float*)d_in[2];
  const float* Wq = (const float*)d_in[3];
  const float* bq = (const float*)d_in[4];
  const float* Wk = (const float*)d_in[5];
  const float* bk = (const float*)d_in[6];
  const float* Wv = (const float*)d_in[7];
  const float* bv = (const float*)d_in[8];
  const float* Wo = (const float*)d_in[9];
  const float* bo = (const float*)d_in[10];
  float* out = (float*)d_out;

  u16* ws = (u16*)d_ws;
  u16* Xq = ws;
  u16* Xk = ws + 4194304;
  u16* Xv = ws + 8388608;
  u16* cWq = ws + 12582912;
  u16* cWk = ws + 13631488;
  u16* cWv = ws + 14680064;
  u16* cWo = ws + 15728640;
  u16* cbq = ws + 16777216;
  u16* cbk = ws + 16779264;
  u16* cbv = ws + 16781312;
  u16* cbo = ws + 16783360;
  u16* Qw = ws + 17301504;
  u16* Kw = ws + 21495808;
  u16* Vtw = ws + 25690112;
  u16* Ow = ws + 29884416;

  cvt_kernel<<<16388, 256, 0, stream>>>(query, key_, value, Wq, Wk, Wv, Wo,
                                        bq, bk, bv, bo, ws);
  qkv_kernel<<<768, 256, 0, stream>>>(Xq, Xk, Xv, cWq, cWk, cWv, cbq, cbk, cbv,
                                      Qw, Kw, Vtw);
  attn_kernel<<<dim3(32, 32), 256, 0, stream>>>(Qw, Kw, Vtw, Ow);
  proj_kernel<<<256, 256, 0, stream>>>(Ow, cWo, cbo, out);
}